// Round 18
// baseline (144.221 us; speedup 1.0000x reference)
//
#include <hip/hip_runtime.h>
#include <math.h>

#define NN 10000
#define NE 160000
#define CAP 64
#define HB 32
#define SCALE_F 0.17677669529663687f
#define LOG2E_F 1.4426950408889634f

typedef _Float16 f16x8 __attribute__((ext_vector_type(8)));
typedef _Float16 f16x2 __attribute__((ext_vector_type(2)));
typedef float f32x4 __attribute__((ext_vector_type(4)));

#if defined(__has_builtin)
#if __has_builtin(__builtin_amdgcn_global_load_lds)
#define HAS_GLL 1
#endif
#if __has_builtin(__builtin_amdgcn_fdot2)
#define HAS_FDOT2 1
#endif
#endif

struct __align__(8) Edge { int s; float pw; };

__device__ __forceinline__ float dot8_f16(f16x8 a, f16x8 b, float acc) {
#ifdef HAS_FDOT2
#pragma unroll
  for (int e = 0; e < 4; ++e) {
    f16x2 aa = {a[2 * e], a[2 * e + 1]};
    f16x2 bb = {b[2 * e], b[2 * e + 1]};
    acc = __builtin_amdgcn_fdot2(aa, bb, acc, false);
  }
#else
#pragma unroll
  for (int e = 0; e < 8; ++e) acc += (float)a[e] * (float)b[e];
#endif
  return acc;
}

// ---------------- bucket scatter, src-partitioned: 2 sub-buckets of 32 per dst ----------------
// half = src>=5000. counts[d*2+half] -> sub-degree. Enables 2-pass L2-resident gat.
__global__ __launch_bounds__(256) void scatter_kernel(const int* __restrict__ src, const int* __restrict__ dst,
                                                      const float* __restrict__ obs, int* __restrict__ counts,
                                                      Edge* __restrict__ edges) {
  int e = blockIdx.x * 256 + threadIdx.x;
  if (e >= NE) return;
  int s = src[e], d = dst[e];
  int half = (s >= NN / 2) ? 1 : 0;
  int p = atomicAdd(&counts[d * 2 + half], 1);
  float dx = obs[d * 37 + 0] - obs[s * 37 + 0];
  float dy = obs[d * 37 + 1] - obs[s * 37 + 1];
  Edge ee;
  ee.s = s;
  ee.pw = SCALE_F * LOG2E_F * __expf(-sqrtf(dx * dx + dy * dy));
  edges[d * CAP + half * HB + p] = ee;
}

// ---------------- fused prep: weights + feature pack + counts zero + out=b3 init ----------------
__global__ __launch_bounds__(256) void prep_kernel(const float* __restrict__ wq0, const float* __restrict__ wk0,
                                                   const float* __restrict__ wv0,
                                                   const float* __restrict__ wo0, const float* __restrict__ wq1,
                                                   const float* __restrict__ wk1, const float* __restrict__ wv1,
                                                   const float* __restrict__ wo1, const float* __restrict__ w1,
                                                   const float* __restrict__ w2, _Float16* __restrict__ dst,
                                                   const float* __restrict__ obs, _Float16* __restrict__ A0,
                                                   int* __restrict__ counts, const float* __restrict__ b3,
                                                   float* __restrict__ outg) {
  int t = blockIdx.x * 256 + threadIdx.x;
  if (t >= 524288) {
    int tp = t - 524288;
    if (tp < NN * 64) { // pack part
      int n = tp >> 6, k = tp & 63;
      const float* o = obs + n * 37;
      float x = 0.f;
      if (k < 12) x = o[k];
      else if (k < 19) x = o[30 + k - 12];
      else if (k < 31) x = o[12 + k - 19];
      else if (k < 35) x = o[26 + k - 31];
      else if (k < 53) x = o[12 + k - 35];
      A0[tp] = (_Float16)x;
      return;
    }
    int tz = tp - NN * 64;
    if (tz < 2 * NN) { counts[tz] = 0; return; }
    int to = tz - 2 * NN;
    if (to < 2 * NN) outg[to] = b3[to & 1];
    return;
  }
  if (t < 98304) { // w0T block-diag [1536][64]
    int c = t >> 6, k = t & 63;
    float x = 0.f;
    if (c < 512) { if (k < 19) x = wq0[k * 512 + c]; }
    else if (c < 1024) { if (k >= 19 && k < 35) x = wk0[(k - 19) * 512 + (c - 512)]; }
    else { if (k >= 35 && k < 53) x = wv0[(k - 35) * 512 + (c - 1024)]; }
    dst[t] = (_Float16)x;
    return;
  }
  int t1 = t - 98304;
  if (t1 < 196608) { // wqkv1T [1536][128]
    int c = t1 >> 7, k = t1 & 127;
    float x;
    if (c < 512) x = wq1[k * 512 + c];
    else if (c < 1024) x = wk1[k * 512 + (c - 512)];
    else x = wv1[k * 512 + (c - 1024)];
    dst[98304 + t1] = (_Float16)x;
    return;
  }
  int t2 = t1 - 196608;
  if (t2 < 65536) { int n = t2 >> 9, k = t2 & 511; dst[294912 + t2] = (_Float16)wo0[k * 128 + n]; return; }
  int t3 = t2 - 65536;
  if (t3 < 65536) { int n = t3 >> 9, k = t3 & 511; dst[360448 + t3] = (_Float16)wo1[k * 128 + n]; return; }
  int t4 = t3 - 65536;
  if (t4 < 32768) { int n = t4 >> 7, k = t4 & 127; dst[425984 + t4] = (_Float16)w1[k * 256 + n]; return; }
  int t5 = t4 - 32768;
  if (t5 < 65536) { int n = t5 >> 8, k = t5 & 255; dst[458752 + t5] = (_Float16)w2[k * 256 + n]; }
}

// ---------------- GAT: XCD-pinned head phases, MAX-FREE softmax, 2-pass src-partitioned ----------------
// qh/attH: [head][n][128]; KV: [head][n][256] k|v interleaved. XCD=bid%8 -> head=(bid%8)&3.
// Pass h gathers only src in [h*5000,(h+1)*5000): per-XCD L2 working set 2.56MB <= 4MB -> L2-hit.
// Max-free accumulate (den/o are plain sums) carries across passes in registers.
__global__ __launch_bounds__(256) void gat_kernel(const _Float16* __restrict__ qh, const _Float16* __restrict__ KV,
                                                  const int* __restrict__ counts, const Edge* __restrict__ edges,
                                                  _Float16* __restrict__ attH) {
  int wave = threadIdx.x >> 6, lane = threadIdx.x & 63;
  int grp = lane >> 4, l15 = lane & 15;
  int r = blockIdx.x & 7;
  int c = blockIdx.x >> 3;
  int head = r & 3;
  int chunk = c * 2 + (r >> 2);
  int n = chunk * 4 + wave;
  const _Float16* kvbase = KV + (size_t)head * NN * 256 + l15 * 8;
  f16x8 qv = *(const f16x8*)(qh + (size_t)head * NN * 128 + n * 128 + l15 * 8);
  int cnt0 = counts[n * 2 + 0];
  int cnt1 = counts[n * 2 + 1];
  const Edge* eb = edges + (size_t)n * CAP;
  float den = 0.f;
  float o[8] = {};
#pragma unroll
  for (int half = 0; half < 2; ++half) {
    int cnt = half ? cnt1 : cnt0;
    const Edge* ebh = eb + half * HB;
    for (int j = grp; j < cnt; j += 8) {
      int jB = j + 4;
      bool actB = jB < cnt;
      int iB = actB ? jB : j;
      Edge eA = ebh[j];
      Edge eB = ebh[iB];
      const _Float16* pA = kvbase + (size_t)eA.s * 256;
      const _Float16* pB = kvbase + (size_t)eB.s * 256;
      f16x8 kA = *(const f16x8*)pA;
      f16x8 kB = *(const f16x8*)pB;
      f16x8 vA = *(const f16x8*)(pA + 128);
      f16x8 vB = *(const f16x8*)(pB + 128);
      float dA = dot8_f16(qv, kA, 0.f);
      float dB = dot8_f16(qv, kB, 0.f);
      dA += __shfl_xor(dA, 1); dB += __shfl_xor(dB, 1);
      dA += __shfl_xor(dA, 2); dB += __shfl_xor(dB, 2);
      dA += __shfl_xor(dA, 4); dB += __shfl_xor(dB, 4);
      dA += __shfl_xor(dA, 8); dB += __shfl_xor(dB, 8);
      float wA = exp2f(fminf(dA * eA.pw, 80.f));
      float wB = actB ? exp2f(fminf(dB * eB.pw, 80.f)) : 0.f;
      den += wA + wB;
#pragma unroll
      for (int e = 0; e < 8; ++e)
        o[e] += wA * (float)vA[e] + wB * (float)vB[e];
    }
  }
#pragma unroll
  for (int off = 16; off <= 32; off <<= 1) {
    den += __shfl_xor(den, off);
#pragma unroll
    for (int e = 0; e < 8; ++e) o[e] += __shfl_xor(o[e], off);
  }
  if (grp == 0) {
    float inv = 1.f / (den + 1e-16f);
    f16x8 rr;
#pragma unroll
    for (int e = 0; e < 8; ++e) rr[e] = (_Float16)(o[e] * inv);
    *(f16x8*)(attH + (size_t)head * NN * 128 + n * 128 + l15 * 8) = rr;
  }
}

// ---------------- MFMA f16 GEMM, double-buffered global_load_lds + XOR-swizzled LDS ----------------
// SPLIT=1: N=1536 qkv -> qh[head][n][128] + KV[head][n][256]. SEGA=1: A head-major [4][NN][128]
// read as [NN][512]. PIN=1: XCD-pinned 1D remap. BM=32 for N=128 wo-GEMMs (CU balance).
template <int BM, int BIAS, int RELU, int SPLIT, int SEGA, int PIN>
__global__ __launch_bounds__(256) void gemm_mfma(const _Float16* __restrict__ A, const _Float16* __restrict__ BT,
                                                 const float* __restrict__ bias, _Float16* __restrict__ C,
                                                 _Float16* __restrict__ KV, int M, int N, int K) {
  constexpr int ACH = BM / 32;
  constexpr int WR = BM / 2;
  constexpr int RF = WR / 16;
  __shared__ _Float16 As[2][BM * 64];
  __shared__ _Float16 Bs[2][64 * 64];
  int tid = threadIdx.x;
  int wave = tid >> 6, lane = tid & 63;
  int l15 = lane & 15, lq = lane >> 4;
  int wr = (wave >> 1) * WR, wc = (wave & 1) * 32;
  int bx, by;
  if (PIN) {
    int xcd = blockIdx.x & 7, slot = blockIdx.x >> 3; // 1896 = 8 x 237
    int hh = xcd & 3, half = xcd >> 2;
    int i = half * 237 + slot;
    int bg = i / 79;
    bx = i - bg * 79;
    by = (bg < 2) ? (2 * hh + bg) : (bg < 4) ? (8 + 2 * hh + (bg - 2)) : (16 + 2 * hh + (bg - 4));
  } else {
    bx = blockIdx.x;
    by = blockIdx.y;
  }
  int m0 = bx * BM, n0 = by * 64;
  f32x4 acc[RF][2] = {};
  int sw = (l15 & 7) << 4;
  int nt = K >> 6;

  auto stage = [&](int buf, int k0) {
#pragma unroll
    for (int i = 0; i < ACH; ++i) {
      int P = (wave * ACH + i) * 1024 + lane * 16;
      int row = P >> 7;
      int cl = (P & 127) ^ ((row & 7) << 4);
      int gr = m0 + row;
      if (gr > M - 1) gr = M - 1;
      const _Float16* g;
      if (SEGA)
        g = A + (size_t)(k0 >> 7) * (NN * 128) + (size_t)gr * 128 + (k0 & 64) + (cl >> 1);
      else
        g = A + (size_t)gr * K + k0 + (cl >> 1);
#ifdef HAS_GLL
      __builtin_amdgcn_global_load_lds((const __attribute__((address_space(1))) void*)g,
                                       (__attribute__((address_space(3))) void*)((char*)As[buf] + (wave * ACH + i) * 1024),
                                       16, 0, 0);
#else
      uint4 tv = *(const uint4*)g;
      *(uint4*)((char*)As[buf] + P) = tv;
#endif
    }
#pragma unroll
    for (int i = 0; i < 2; ++i) {
      int P = (wave * 2 + i) * 1024 + lane * 16;
      int row = P >> 7;
      int cl = (P & 127) ^ ((row & 7) << 4);
      const _Float16* g = BT + (size_t)(n0 + row) * K + k0 + (cl >> 1);
#ifdef HAS_GLL
      __builtin_amdgcn_global_load_lds((const __attribute__((address_space(1))) void*)g,
                                       (__attribute__((address_space(3))) void*)((char*)Bs[buf] + (wave * 2 + i) * 1024),
                                       16, 0, 0);
#else
      uint4 tv = *(const uint4*)g;
      *(uint4*)((char*)Bs[buf] + P) = tv;
#endif
    }
  };

  stage(0, 0);
  __syncthreads();
  for (int t = 0; t < nt; ++t) {
    int cur = t & 1;
    if (t + 1 < nt) stage(cur ^ 1, (t + 1) << 6);
    const char* pa = (const char*)As[cur];
    const char* pb = (const char*)Bs[cur];
#pragma unroll
    for (int ks = 0; ks < 2; ++ks) {
      int cc = ((ks * 32 + lq * 8) << 1) ^ sw;
      f16x8 b0 = *(const f16x8*)(pb + (wc + 0 + l15) * 128 + cc);
      f16x8 b1 = *(const f16x8*)(pb + (wc + 16 + l15) * 128 + cc);
#pragma unroll
      for (int ri = 0; ri < RF; ++ri) {
        f16x8 a0 = *(const f16x8*)(pa + (wr + ri * 16 + l15) * 128 + cc);
        acc[ri][0] = __builtin_amdgcn_mfma_f32_16x16x32_f16(a0, b0, acc[ri][0], 0, 0, 0);
        acc[ri][1] = __builtin_amdgcn_mfma_f32_16x16x32_f16(a0, b1, acc[ri][1], 0, 0, 0);
      }
    }
    __syncthreads();
  }
#pragma unroll
  for (int ri = 0; ri < RF; ++ri) {
    int gr0 = m0 + wr + ri * 16 + lq * 4;
#pragma unroll
    for (int ci = 0; ci < 2; ++ci) {
      int gc = n0 + wc + ci * 16 + l15;
      float bb = 0.f;
      if (BIAS) bb = bias[gc];
#pragma unroll
      for (int jj = 0; jj < 4; ++jj) {
        int gr = gr0 + jj;
        float x = acc[ri][ci][jj] + bb;
        if (RELU) x = fmaxf(x, 0.f);
        if (gr < M) {
          _Float16 val = (_Float16)x;
          if (SPLIT) {
            if (gc < 512) {
              int hh = gc >> 7, ch = gc & 127;
              C[((size_t)hh * NN + gr) * 128 + ch] = val;
            } else if (gc < 1024) {
              int hh = (gc - 512) >> 7, ch = (gc - 512) & 127;
              KV[((size_t)hh * NN + gr) * 256 + ch] = val;
            } else {
              int hh = (gc - 1024) >> 7, ch = (gc - 1024) & 127;
              KV[((size_t)hh * NN + gr) * 256 + 128 + ch] = val;
            }
          } else {
            C[(size_t)gr * N + gc] = val;
          }
        }
      }
    }
  }
}

// ---------------- fused MLP: out += relu(relu(h@w1T+b1)@w2T+b2)@w3, per 32-row block ----------------
__global__ __launch_bounds__(256) void mlp_kernel(const _Float16* __restrict__ h, const _Float16* __restrict__ w1T,
                                                  const float* __restrict__ b1, const _Float16* __restrict__ w2T,
                                                  const float* __restrict__ b2, const float* __restrict__ w3,
                                                  float* __restrict__ outg) {
  __shared__ __align__(16) char lds[73728];
  const int LDS_H = 0, LDS_W1 = 8192, LDS_M1 = 0, LDS_W2 = 16384;
  int tid = threadIdx.x;
  int wave = tid >> 6, lane = tid & 63;
  int l15 = lane & 15, lq = lane >> 4;
  int m0 = blockIdx.x * 32;
  int wn = wave * 64;

#pragma unroll
  for (int i = 0; i < 2; ++i) {
    int P = (wave * 2 + i) * 1024 + lane * 16;
    int row = P >> 8;
    int cl = (P & 255) ^ ((row & 15) << 4);
    int gr = m0 + row;
    if (gr > NN - 1) gr = NN - 1;
    const _Float16* g = h + (size_t)gr * 128 + (cl >> 1);
#ifdef HAS_GLL
    __builtin_amdgcn_global_load_lds((const __attribute__((address_space(1))) void*)g,
                                     (__attribute__((address_space(3))) void*)(lds + LDS_H + (wave * 2 + i) * 1024),
                                     16, 0, 0);
#else
    *(uint4*)(lds + LDS_H + P) = *(const uint4*)g;
#endif
  }
#pragma unroll
  for (int i = 0; i < 16; ++i) {
    int P = (wave * 16 + i) * 1024 + lane * 16;
    int row = P >> 8;
    int cl = (P & 255) ^ ((row & 15) << 4);
    const _Float16* g = w1T + (size_t)row * 128 + (cl >> 1);
#ifdef HAS_GLL
    __builtin_amdgcn_global_load_lds((const __attribute__((address_space(1))) void*)g,
                                     (__attribute__((address_space(3))) void*)(lds + LDS_W1 + (wave * 16 + i) * 1024),
                                     16, 0, 0);
#else
    *(uint4*)(lds + LDS_W1 + P) = *(const uint4*)g;
#endif
  }
  __syncthreads();

  f32x4 acc1[2][4] = {};
#pragma unroll
  for (int ks = 0; ks < 4; ++ks) {
    int kcb = (ks * 32 + lq * 8) << 1;
    f16x8 bfr[4];
#pragma unroll
    for (int ci = 0; ci < 4; ++ci) {
      int brow = wn + ci * 16 + l15;
      bfr[ci] = *(const f16x8*)(lds + LDS_W1 + brow * 256 + (kcb ^ ((brow & 15) << 4)));
    }
#pragma unroll
    for (int ri = 0; ri < 2; ++ri) {
      int arow = ri * 16 + l15;
      f16x8 a = *(const f16x8*)(lds + LDS_H + arow * 256 + (kcb ^ ((arow & 15) << 4)));
#pragma unroll
      for (int ci = 0; ci < 4; ++ci)
        acc1[ri][ci] = __builtin_amdgcn_mfma_f32_16x16x32_f16(a, bfr[ci], acc1[ri][ci], 0, 0, 0);
    }
  }
  __syncthreads();
#pragma unroll
  for (int ri = 0; ri < 2; ++ri) {
#pragma unroll
    for (int ci = 0; ci < 4; ++ci) {
      int ncol = wn + ci * 16 + l15;
      float bb = b1[ncol];
#pragma unroll
      for (int j = 0; j < 4; ++j) {
        int mrow = ri * 16 + lq * 4 + j;
        float x = fmaxf(acc1[ri][ci][j] + bb, 0.f);
        *(_Float16*)(lds + LDS_M1 + mrow * 512 + ((ncol * 2) ^ ((mrow & 15) << 4))) = (_Float16)x;
      }
    }
  }
  __syncthreads();

  f32x4 acc2[2][4] = {};
  for (int ks = 0; ks < 4; ++ks) {
#pragma unroll
    for (int i = 0; i < 8; ++i) {
      int P = (wave * 8 + i) * 1024 + lane * 16;
      int row = P >> 7;
      int cl = (P & 127) ^ ((row & 7) << 4);
      const _Float16* g = w2T + (size_t)row * 256 + ks * 64 + (cl >> 1);
#ifdef HAS_GLL
      __builtin_amdgcn_global_load_lds((const __attribute__((address_space(1))) void*)g,
                                       (__attribute__((address_space(3))) void*)(lds + LDS_W2 + (wave * 8 + i) * 1024),
                                       16, 0, 0);
#else
      *(uint4*)(lds + LDS_W2 + P) = *(const uint4*)g;
#endif
    }
    __syncthreads();
#pragma unroll
    for (int kk = 0; kk < 2; ++kk) {
      int kglob = (ks * 64 + kk * 32 + lq * 8) << 1;
      int kcb2 = (kk * 32 + lq * 8) << 1;
      f16x8 bfr[4];
#pragma unroll
      for (int ci = 0; ci < 4; ++ci) {
        int brow = wn + ci * 16 + l15;
        bfr[ci] = *(const f16x8*)(lds + LDS_W2 + brow * 128 + (kcb2 ^ ((brow & 7) << 4)));
      }
#pragma unroll
      for (int ri = 0; ri < 2; ++ri) {
        int arow = ri * 16 + l15;
        f16x8 a = *(const f16x8*)(lds + LDS_M1 + arow * 512 + (kglob ^ ((arow & 15) << 4)));
#pragma unroll
        for (int ci = 0; ci < 4; ++ci)
          acc2[ri][ci] = __builtin_amdgcn_mfma_f32_16x16x32_f16(a, bfr[ci], acc2[ri][ci], 0, 0, 0);
      }
    }
    __syncthreads();
  }

  float p0[2][4] = {}, p1[2][4] = {};
#pragma unroll
  for (int ri = 0; ri < 2; ++ri) {
#pragma unroll
    for (int ci = 0; ci < 4; ++ci) {
      int ncol = wn + ci * 16 + l15;
      float bb = b2[ncol];
      float w30 = w3[ncol * 2 + 0], w31 = w3[ncol * 2 + 1];
#pragma unroll
      for (int j = 0; j < 4; ++j) {
        float x = fmaxf(acc2[ri][ci][j] + bb, 0.f);
        p0[ri][j] += x * w30;
        p1[ri][j] += x * w31;
      }
    }
  }
#pragma unroll
  for (int ri = 0; ri < 2; ++ri) {
#pragma unroll
    for (int j = 0; j < 4; ++j) {
#pragma unroll
      for (int off = 1; off <= 8; off <<= 1) {
        p0[ri][j] += __shfl_xor(p0[ri][j], off);
        p1[ri][j] += __shfl_xor(p1[ri][j], off);
      }
      int gr = m0 + ri * 16 + lq * 4 + j;
      if (l15 == 0 && gr < NN) {
        atomicAdd(&outg[gr * 2 + 0], p0[ri][j]);
        atomicAdd(&outg[gr * 2 + 1], p1[ri][j]);
      }
    }
  }
}

extern "C" void kernel_launch(void* const* d_in, const int* in_sizes, int n_in,
                              void* d_out, int out_size, void* d_ws, size_t ws_size,
                              hipStream_t stream) {
  const float* obs = (const float*)d_in[0];
  const int* eidx = (const int*)d_in[1];
  const float* wq0 = (const float*)d_in[2];
  const float* wk0 = (const float*)d_in[3];
  const float* wv0 = (const float*)d_in[4];
  const float* wo0 = (const float*)d_in[5];
  const float* bo0 = (const float*)d_in[6];
  const float* wq1 = (const float*)d_in[7];
  const float* wk1 = (const float*)d_in[8];
  const float* wv1 = (const float*)d_in[9];
  const float* wo1 = (const float*)d_in[10];
  const float* bo1 = (const float*)d_in[11];
  const float* w1 = (const float*)d_in[12];
  const float* b1 = (const float*)d_in[13];
  const float* w2 = (const float*)d_in[14];
  const float* b2 = (const float*)d_in[15];
  const float* w3 = (const float*)d_in[16];
  const float* b3 = (const float*)d_in[17];
  float* outp = (float*)d_out;

  char* wsb = (char*)d_ws;
  _Float16* qh = (_Float16*)(wsb + 0);           // [4][10000][128]
  _Float16* KVB = (_Float16*)(wsb + 10240000);   // [4][10000][256] k|v interleaved
  _Float16* attH = (_Float16*)(wsb + 30720000);  // [4][10000][128]
  _Float16* h = (_Float16*)(wsb + 40960000);     // 10000x128
  _Float16* A0 = (_Float16*)(wsb + 43520000);    // 10000x64
  _Float16* wT = (_Float16*)(wsb + 44800000);    // 524288 f16
  int* counts = (int*)(wsb + 45848576);          // 10000 x 2
  Edge* edges = (Edge*)(wsb + 45928576);         // 10000 x CAP(64) x 8B = 5.12 MB

  _Float16* w0T = wT + 0;        // [1536][64]
  _Float16* wqkv1T = wT + 98304; // [1536][128]
  _Float16* wo0T = wT + 294912;  // [128][512]
  _Float16* wo1T = wT + 360448;  // [128][512]
  _Float16* w1T = wT + 425984;   // [256][128]
  _Float16* w2T = wT + 458752;   // [256][256]

  const int* e_src = eidx;
  const int* e_dst = eidx + NE;

  // fused prep (weights + pack + counts zero + out=b3), then src-partitioned bucket scatter
  prep_kernel<<<4705, 256, 0, stream>>>(wq0, wk0, wv0, wo0, wq1, wk1, wv1, wo1, w1, w2, wT, obs, A0,
                                        counts, b3, outp);
  scatter_kernel<<<(NE + 255) / 256, 256, 0, stream>>>(e_src, e_dst, obs, counts, edges);

  // layer 0: qkv (XCD-pinned SPLIT), 2-pass GAT, out-proj (segmented head-major A, BM=32)
  gemm_mfma<128, 0, 0, 1, 0, 1><<<1896, 256, 0, stream>>>(A0, w0T, nullptr, qh, KVB, NN, 1536, 64);
  gat_kernel<<<10000, 256, 0, stream>>>(qh, KVB, counts, edges, attH);
  gemm_mfma<32, 1, 0, 0, 1, 0><<<dim3(313, 2), 256, 0, stream>>>(attH, wo0T, bo0, h, nullptr, NN, 128, 512);

  // layer 1
  gemm_mfma<128, 0, 0, 1, 0, 1><<<1896, 256, 0, stream>>>(h, wqkv1T, nullptr, qh, KVB, NN, 1536, 128);
  gat_kernel<<<10000, 256, 0, stream>>>(qh, KVB, counts, edges, attH);
  gemm_mfma<32, 1, 0, 0, 1, 0><<<dim3(313, 2), 256, 0, stream>>>(attH, wo1T, bo1, h, nullptr, NN, 128, 512);

  // fused MLP: w1+w2+w3 in one kernel (out pre-initialized to b3)
  mlp_kernel<<<313, 256, 0, stream>>>(h, w1T, b1, w2T, b2, w3, outp);
}

// Round 19
// 140.502 us; speedup vs baseline: 1.0265x; 1.0265x over previous
//
#include <hip/hip_runtime.h>
#include <math.h>

#define NN 10000
#define NE 160000
#define CAP 64
#define SCALE_F 0.17677669529663687f
#define LOG2E_F 1.4426950408889634f

typedef _Float16 f16x8 __attribute__((ext_vector_type(8)));
typedef _Float16 f16x2 __attribute__((ext_vector_type(2)));
typedef float f32x4 __attribute__((ext_vector_type(4)));

#if defined(__has_builtin)
#if __has_builtin(__builtin_amdgcn_global_load_lds)
#define HAS_GLL 1
#endif
#if __has_builtin(__builtin_amdgcn_fdot2)
#define HAS_FDOT2 1
#endif
#endif

struct __align__(8) Edge { int s; float pw; };

__device__ __forceinline__ float dot8_f16(f16x8 a, f16x8 b, float acc) {
#ifdef HAS_FDOT2
#pragma unroll
  for (int e = 0; e < 4; ++e) {
    f16x2 aa = {a[2 * e], a[2 * e + 1]};
    f16x2 bb = {b[2 * e], b[2 * e + 1]};
    acc = __builtin_amdgcn_fdot2(aa, bb, acc, false);
  }
#else
#pragma unroll
  for (int e = 0; e < 8; ++e) acc += (float)a[e] * (float)b[e];
#endif
  return acc;
}

// ---------------- bucket scatter (no CSR scan; CAP=64 >> max degree ~45) ----------------
__global__ __launch_bounds__(256) void scatter_kernel(const int* __restrict__ src, const int* __restrict__ dst,
                                                      const float* __restrict__ obs, int* __restrict__ counts,
                                                      Edge* __restrict__ edges) {
  int e = blockIdx.x * 256 + threadIdx.x;
  if (e >= NE) return;
  int s = src[e], d = dst[e];
  int p = atomicAdd(&counts[d], 1);
  float dx = obs[d * 37 + 0] - obs[s * 37 + 0];
  float dy = obs[d * 37 + 1] - obs[s * 37 + 1];
  Edge ee;
  ee.s = s;
  ee.pw = SCALE_F * LOG2E_F * __expf(-sqrtf(dx * dx + dy * dy));
  edges[d * CAP + p] = ee;
}

// ---------------- fused prep: weights + feature pack + counts zero + out=b3 init ----------------
__global__ __launch_bounds__(256) void prep_kernel(const float* __restrict__ wq0, const float* __restrict__ wk0,
                                                   const float* __restrict__ wv0,
                                                   const float* __restrict__ wo0, const float* __restrict__ wq1,
                                                   const float* __restrict__ wk1, const float* __restrict__ wv1,
                                                   const float* __restrict__ wo1, const float* __restrict__ w1,
                                                   const float* __restrict__ w2, _Float16* __restrict__ dst,
                                                   const float* __restrict__ obs, _Float16* __restrict__ A0,
                                                   int* __restrict__ counts, const float* __restrict__ b3,
                                                   float* __restrict__ outg) {
  int t = blockIdx.x * 256 + threadIdx.x;
  if (t >= 524288) {
    int tp = t - 524288;
    if (tp < NN * 64) { // pack part
      int n = tp >> 6, k = tp & 63;
      const float* o = obs + n * 37;
      float x = 0.f;
      if (k < 12) x = o[k];
      else if (k < 19) x = o[30 + k - 12];
      else if (k < 31) x = o[12 + k - 19];
      else if (k < 35) x = o[26 + k - 31];
      else if (k < 53) x = o[12 + k - 35];
      A0[tp] = (_Float16)x;
      return;
    }
    int tz = tp - NN * 64;
    if (tz < NN) { counts[tz] = 0; return; }
    int to = tz - NN;
    if (to < 2 * NN) outg[to] = b3[to & 1];
    return;
  }
  if (t < 98304) { // w0T block-diag [1536][64]
    int c = t >> 6, k = t & 63;
    float x = 0.f;
    if (c < 512) { if (k < 19) x = wq0[k * 512 + c]; }
    else if (c < 1024) { if (k >= 19 && k < 35) x = wk0[(k - 19) * 512 + (c - 512)]; }
    else { if (k >= 35 && k < 53) x = wv0[(k - 35) * 512 + (c - 1024)]; }
    dst[t] = (_Float16)x;
    return;
  }
  int t1 = t - 98304;
  if (t1 < 196608) { // wqkv1T [1536][128]
    int c = t1 >> 7, k = t1 & 127;
    float x;
    if (c < 512) x = wq1[k * 512 + c];
    else if (c < 1024) x = wk1[k * 512 + (c - 512)];
    else x = wv1[k * 512 + (c - 1024)];
    dst[98304 + t1] = (_Float16)x;
    return;
  }
  int t2 = t1 - 196608;
  if (t2 < 65536) { int n = t2 >> 9, k = t2 & 511; dst[294912 + t2] = (_Float16)wo0[k * 128 + n]; return; }
  int t3 = t2 - 65536;
  if (t3 < 65536) { int n = t3 >> 9, k = t3 & 511; dst[360448 + t3] = (_Float16)wo1[k * 128 + n]; return; }
  int t4 = t3 - 65536;
  if (t4 < 32768) { int n = t4 >> 7, k = t4 & 127; dst[425984 + t4] = (_Float16)w1[k * 256 + n]; return; }
  int t5 = t4 - 32768;
  if (t5 < 65536) { int n = t5 >> 8, k = t5 & 255; dst[458752 + t5] = (_Float16)w2[k * 256 + n]; }
}

// ---------------- GAT edge kernel: XCD-pinned head phases, MAX-FREE softmax, interleaved KV ----------------
__global__ __launch_bounds__(256) void gat_kernel(const _Float16* __restrict__ qh, const _Float16* __restrict__ KV,
                                                  const int* __restrict__ counts, const Edge* __restrict__ edges,
                                                  _Float16* __restrict__ attH) {
  int wave = threadIdx.x >> 6, lane = threadIdx.x & 63;
  int grp = lane >> 4, l15 = lane & 15;
  int r = blockIdx.x & 7;
  int c = blockIdx.x >> 3;
  int head = r & 3;
  int chunk = c * 2 + (r >> 2);
  int n = chunk * 4 + wave;
  const _Float16* kvbase = KV + (size_t)head * NN * 256 + l15 * 8;
  f16x8 qv = *(const f16x8*)(qh + (size_t)head * NN * 128 + n * 128 + l15 * 8);
  int cnt = counts[n];
  const Edge* eb = edges + (size_t)n * CAP;
  float den = 0.f;
  float o[8] = {};
  for (int j = grp; j < cnt; j += 8) {
    int jB = j + 4;
    bool actB = jB < cnt;
    int iB = actB ? jB : j;
    Edge eA = eb[j];
    Edge eB = eb[iB];
    const _Float16* pA = kvbase + (size_t)eA.s * 256;
    const _Float16* pB = kvbase + (size_t)eB.s * 256;
    f16x8 kA = *(const f16x8*)pA;
    f16x8 kB = *(const f16x8*)pB;
    f16x8 vA = *(const f16x8*)(pA + 128);
    f16x8 vB = *(const f16x8*)(pB + 128);
    float dA = dot8_f16(qv, kA, 0.f);
    float dB = dot8_f16(qv, kB, 0.f);
    dA += __shfl_xor(dA, 1); dB += __shfl_xor(dB, 1);
    dA += __shfl_xor(dA, 2); dB += __shfl_xor(dB, 2);
    dA += __shfl_xor(dA, 4); dB += __shfl_xor(dB, 4);
    dA += __shfl_xor(dA, 8); dB += __shfl_xor(dB, 8);
    float wA = exp2f(fminf(dA * eA.pw, 80.f));
    float wB = actB ? exp2f(fminf(dB * eB.pw, 80.f)) : 0.f;
    den += wA + wB;
#pragma unroll
    for (int e = 0; e < 8; ++e)
      o[e] += wA * (float)vA[e] + wB * (float)vB[e];
  }
#pragma unroll
  for (int off = 16; off <= 32; off <<= 1) {
    den += __shfl_xor(den, off);
#pragma unroll
    for (int e = 0; e < 8; ++e) o[e] += __shfl_xor(o[e], off);
  }
  if (grp == 0) {
    float inv = 1.f / (den + 1e-16f);
    f16x8 rr;
#pragma unroll
    for (int e = 0; e < 8; ++e) rr[e] = (_Float16)(o[e] * inv);
    *(f16x8*)(attH + (size_t)head * NN * 128 + n * 128 + l15 * 8) = rr;
  }
}

// ---------------- MFMA f16 GEMM, double-buffered global_load_lds + XOR-swizzled LDS ----------------
// SPLIT=1: N=1536 qkv -> qh[head][n][128] + KV[head][n][256]. SEGA=1: A head-major [4][NN][128]
// read as [NN][512]. PIN=1: XCD-pinned 1D remap. BM=32 for N=128 wo-GEMMs (CU balance).
template <int BM, int BIAS, int RELU, int SPLIT, int SEGA, int PIN>
__global__ __launch_bounds__(256) void gemm_mfma(const _Float16* __restrict__ A, const _Float16* __restrict__ BT,
                                                 const float* __restrict__ bias, _Float16* __restrict__ C,
                                                 _Float16* __restrict__ KV, int M, int N, int K) {
  constexpr int ACH = BM / 32;
  constexpr int WR = BM / 2;
  constexpr int RF = WR / 16;
  __shared__ _Float16 As[2][BM * 64];
  __shared__ _Float16 Bs[2][64 * 64];
  int tid = threadIdx.x;
  int wave = tid >> 6, lane = tid & 63;
  int l15 = lane & 15, lq = lane >> 4;
  int wr = (wave >> 1) * WR, wc = (wave & 1) * 32;
  int bx, by;
  if (PIN) {
    int xcd = blockIdx.x & 7, slot = blockIdx.x >> 3; // 1896 = 8 x 237
    int hh = xcd & 3, half = xcd >> 2;
    int i = half * 237 + slot;
    int bg = i / 79;
    bx = i - bg * 79;
    by = (bg < 2) ? (2 * hh + bg) : (bg < 4) ? (8 + 2 * hh + (bg - 2)) : (16 + 2 * hh + (bg - 4));
  } else {
    bx = blockIdx.x;
    by = blockIdx.y;
  }
  int m0 = bx * BM, n0 = by * 64;
  f32x4 acc[RF][2] = {};
  int sw = (l15 & 7) << 4;
  int nt = K >> 6;

  auto stage = [&](int buf, int k0) {
#pragma unroll
    for (int i = 0; i < ACH; ++i) {
      int P = (wave * ACH + i) * 1024 + lane * 16;
      int row = P >> 7;
      int cl = (P & 127) ^ ((row & 7) << 4);
      int gr = m0 + row;
      if (gr > M - 1) gr = M - 1;
      const _Float16* g;
      if (SEGA)
        g = A + (size_t)(k0 >> 7) * (NN * 128) + (size_t)gr * 128 + (k0 & 64) + (cl >> 1);
      else
        g = A + (size_t)gr * K + k0 + (cl >> 1);
#ifdef HAS_GLL
      __builtin_amdgcn_global_load_lds((const __attribute__((address_space(1))) void*)g,
                                       (__attribute__((address_space(3))) void*)((char*)As[buf] + (wave * ACH + i) * 1024),
                                       16, 0, 0);
#else
      uint4 tv = *(const uint4*)g;
      *(uint4*)((char*)As[buf] + P) = tv;
#endif
    }
#pragma unroll
    for (int i = 0; i < 2; ++i) {
      int P = (wave * 2 + i) * 1024 + lane * 16;
      int row = P >> 7;
      int cl = (P & 127) ^ ((row & 7) << 4);
      const _Float16* g = BT + (size_t)(n0 + row) * K + k0 + (cl >> 1);
#ifdef HAS_GLL
      __builtin_amdgcn_global_load_lds((const __attribute__((address_space(1))) void*)g,
                                       (__attribute__((address_space(3))) void*)((char*)Bs[buf] + (wave * 2 + i) * 1024),
                                       16, 0, 0);
#else
      uint4 tv = *(const uint4*)g;
      *(uint4*)((char*)Bs[buf] + P) = tv;
#endif
    }
  };

  stage(0, 0);
  __syncthreads();
  for (int t = 0; t < nt; ++t) {
    int cur = t & 1;
    if (t + 1 < nt) stage(cur ^ 1, (t + 1) << 6);
    const char* pa = (const char*)As[cur];
    const char* pb = (const char*)Bs[cur];
#pragma unroll
    for (int ks = 0; ks < 2; ++ks) {
      int cc = ((ks * 32 + lq * 8) << 1) ^ sw;
      f16x8 b0 = *(const f16x8*)(pb + (wc + 0 + l15) * 128 + cc);
      f16x8 b1 = *(const f16x8*)(pb + (wc + 16 + l15) * 128 + cc);
#pragma unroll
      for (int ri = 0; ri < RF; ++ri) {
        f16x8 a0 = *(const f16x8*)(pa + (wr + ri * 16 + l15) * 128 + cc);
        acc[ri][0] = __builtin_amdgcn_mfma_f32_16x16x32_f16(a0, b0, acc[ri][0], 0, 0, 0);
        acc[ri][1] = __builtin_amdgcn_mfma_f32_16x16x32_f16(a0, b1, acc[ri][1], 0, 0, 0);
      }
    }
    __syncthreads();
  }
#pragma unroll
  for (int ri = 0; ri < RF; ++ri) {
    int gr0 = m0 + wr + ri * 16 + lq * 4;
#pragma unroll
    for (int ci = 0; ci < 2; ++ci) {
      int gc = n0 + wc + ci * 16 + l15;
      float bb = 0.f;
      if (BIAS) bb = bias[gc];
#pragma unroll
      for (int jj = 0; jj < 4; ++jj) {
        int gr = gr0 + jj;
        float x = acc[ri][ci][jj] + bb;
        if (RELU) x = fmaxf(x, 0.f);
        if (gr < M) {
          _Float16 val = (_Float16)x;
          if (SPLIT) {
            if (gc < 512) {
              int hh = gc >> 7, ch = gc & 127;
              C[((size_t)hh * NN + gr) * 128 + ch] = val;
            } else if (gc < 1024) {
              int hh = (gc - 512) >> 7, ch = (gc - 512) & 127;
              KV[((size_t)hh * NN + gr) * 256 + ch] = val;
            } else {
              int hh = (gc - 1024) >> 7, ch = (gc - 1024) & 127;
              KV[((size_t)hh * NN + gr) * 256 + 128 + ch] = val;
            }
          } else {
            C[(size_t)gr * N + gc] = val;
          }
        }
      }
    }
  }
}

// ---------------- fused MLP: out += relu(relu(h@w1T+b1)@w2T+b2)@w3, per 32-row block ----------------
__global__ __launch_bounds__(256) void mlp_kernel(const _Float16* __restrict__ h, const _Float16* __restrict__ w1T,
                                                  const float* __restrict__ b1, const _Float16* __restrict__ w2T,
                                                  const float* __restrict__ b2, const float* __restrict__ w3,
                                                  float* __restrict__ outg) {
  __shared__ __align__(16) char lds[73728];
  const int LDS_H = 0, LDS_W1 = 8192, LDS_M1 = 0, LDS_W2 = 16384;
  int tid = threadIdx.x;
  int wave = tid >> 6, lane = tid & 63;
  int l15 = lane & 15, lq = lane >> 4;
  int m0 = blockIdx.x * 32;
  int wn = wave * 64;

#pragma unroll
  for (int i = 0; i < 2; ++i) {
    int P = (wave * 2 + i) * 1024 + lane * 16;
    int row = P >> 8;
    int cl = (P & 255) ^ ((row & 15) << 4);
    int gr = m0 + row;
    if (gr > NN - 1) gr = NN - 1;
    const _Float16* g = h + (size_t)gr * 128 + (cl >> 1);
#ifdef HAS_GLL
    __builtin_amdgcn_global_load_lds((const __attribute__((address_space(1))) void*)g,
                                     (__attribute__((address_space(3))) void*)(lds + LDS_H + (wave * 2 + i) * 1024),
                                     16, 0, 0);
#else
    *(uint4*)(lds + LDS_H + P) = *(const uint4*)g;
#endif
  }
#pragma unroll
  for (int i = 0; i < 16; ++i) {
    int P = (wave * 16 + i) * 1024 + lane * 16;
    int row = P >> 8;
    int cl = (P & 255) ^ ((row & 15) << 4);
    const _Float16* g = w1T + (size_t)row * 128 + (cl >> 1);
#ifdef HAS_GLL
    __builtin_amdgcn_global_load_lds((const __attribute__((address_space(1))) void*)g,
                                     (__attribute__((address_space(3))) void*)(lds + LDS_W1 + (wave * 16 + i) * 1024),
                                     16, 0, 0);
#else
    *(uint4*)(lds + LDS_W1 + P) = *(const uint4*)g;
#endif
  }
  __syncthreads();

  f32x4 acc1[2][4] = {};
#pragma unroll
  for (int ks = 0; ks < 4; ++ks) {
    int kcb = (ks * 32 + lq * 8) << 1;
    f16x8 bfr[4];
#pragma unroll
    for (int ci = 0; ci < 4; ++ci) {
      int brow = wn + ci * 16 + l15;
      bfr[ci] = *(const f16x8*)(lds + LDS_W1 + brow * 256 + (kcb ^ ((brow & 15) << 4)));
    }
#pragma unroll
    for (int ri = 0; ri < 2; ++ri) {
      int arow = ri * 16 + l15;
      f16x8 a = *(const f16x8*)(lds + LDS_H + arow * 256 + (kcb ^ ((arow & 15) << 4)));
#pragma unroll
      for (int ci = 0; ci < 4; ++ci)
        acc1[ri][ci] = __builtin_amdgcn_mfma_f32_16x16x32_f16(a, bfr[ci], acc1[ri][ci], 0, 0, 0);
    }
  }
  __syncthreads();
#pragma unroll
  for (int ri = 0; ri < 2; ++ri) {
#pragma unroll
    for (int ci = 0; ci < 4; ++ci) {
      int ncol = wn + ci * 16 + l15;
      float bb = b1[ncol];
#pragma unroll
      for (int j = 0; j < 4; ++j) {
        int mrow = ri * 16 + lq * 4 + j;
        float x = fmaxf(acc1[ri][ci][j] + bb, 0.f);
        *(_Float16*)(lds + LDS_M1 + mrow * 512 + ((ncol * 2) ^ ((mrow & 15) << 4))) = (_Float16)x;
      }
    }
  }
  __syncthreads();

  f32x4 acc2[2][4] = {};
  for (int ks = 0; ks < 4; ++ks) {
#pragma unroll
    for (int i = 0; i < 8; ++i) {
      int P = (wave * 8 + i) * 1024 + lane * 16;
      int row = P >> 7;
      int cl = (P & 127) ^ ((row & 7) << 4);
      const _Float16* g = w2T + (size_t)row * 256 + ks * 64 + (cl >> 1);
#ifdef HAS_GLL
      __builtin_amdgcn_global_load_lds((const __attribute__((address_space(1))) void*)g,
                                       (__attribute__((address_space(3))) void*)(lds + LDS_W2 + (wave * 8 + i) * 1024),
                                       16, 0, 0);
#else
      *(uint4*)(lds + LDS_W2 + P) = *(const uint4*)g;
#endif
    }
    __syncthreads();
#pragma unroll
    for (int kk = 0; kk < 2; ++kk) {
      int kglob = (ks * 64 + kk * 32 + lq * 8) << 1;
      int kcb2 = (kk * 32 + lq * 8) << 1;
      f16x8 bfr[4];
#pragma unroll
      for (int ci = 0; ci < 4; ++ci) {
        int brow = wn + ci * 16 + l15;
        bfr[ci] = *(const f16x8*)(lds + LDS_W2 + brow * 128 + (kcb2 ^ ((brow & 7) << 4)));
      }
#pragma unroll
      for (int ri = 0; ri < 2; ++ri) {
        int arow = ri * 16 + l15;
        f16x8 a = *(const f16x8*)(lds + LDS_M1 + arow * 512 + (kglob ^ ((arow & 15) << 4)));
#pragma unroll
        for (int ci = 0; ci < 4; ++ci)
          acc2[ri][ci] = __builtin_amdgcn_mfma_f32_16x16x32_f16(a, bfr[ci], acc2[ri][ci], 0, 0, 0);
      }
    }
    __syncthreads();
  }

  float p0[2][4] = {}, p1[2][4] = {};
#pragma unroll
  for (int ri = 0; ri < 2; ++ri) {
#pragma unroll
    for (int ci = 0; ci < 4; ++ci) {
      int ncol = wn + ci * 16 + l15;
      float bb = b2[ncol];
      float w30 = w3[ncol * 2 + 0], w31 = w3[ncol * 2 + 1];
#pragma unroll
      for (int j = 0; j < 4; ++j) {
        float x = fmaxf(acc2[ri][ci][j] + bb, 0.f);
        p0[ri][j] += x * w30;
        p1[ri][j] += x * w31;
      }
    }
  }
#pragma unroll
  for (int ri = 0; ri < 2; ++ri) {
#pragma unroll
    for (int j = 0; j < 4; ++j) {
#pragma unroll
      for (int off = 1; off <= 8; off <<= 1) {
        p0[ri][j] += __shfl_xor(p0[ri][j], off);
        p1[ri][j] += __shfl_xor(p1[ri][j], off);
      }
      int gr = m0 + ri * 16 + lq * 4 + j;
      if (l15 == 0 && gr < NN) {
        atomicAdd(&outg[gr * 2 + 0], p0[ri][j]);
        atomicAdd(&outg[gr * 2 + 1], p1[ri][j]);
      }
    }
  }
}

extern "C" void kernel_launch(void* const* d_in, const int* in_sizes, int n_in,
                              void* d_out, int out_size, void* d_ws, size_t ws_size,
                              hipStream_t stream) {
  const float* obs = (const float*)d_in[0];
  const int* eidx = (const int*)d_in[1];
  const float* wq0 = (const float*)d_in[2];
  const float* wk0 = (const float*)d_in[3];
  const float* wv0 = (const float*)d_in[4];
  const float* wo0 = (const float*)d_in[5];
  const float* bo0 = (const float*)d_in[6];
  const float* wq1 = (const float*)d_in[7];
  const float* wk1 = (const float*)d_in[8];
  const float* wv1 = (const float*)d_in[9];
  const float* wo1 = (const float*)d_in[10];
  const float* bo1 = (const float*)d_in[11];
  const float* w1 = (const float*)d_in[12];
  const float* b1 = (const float*)d_in[13];
  const float* w2 = (const float*)d_in[14];
  const float* b2 = (const float*)d_in[15];
  const float* w3 = (const float*)d_in[16];
  const float* b3 = (const float*)d_in[17];
  float* outp = (float*)d_out;

  char* wsb = (char*)d_ws;
  _Float16* qh = (_Float16*)(wsb + 0);           // [4][10000][128]
  _Float16* KVB = (_Float16*)(wsb + 10240000);   // [4][10000][256] k|v interleaved
  _Float16* attH = (_Float16*)(wsb + 30720000);  // [4][10000][128]
  _Float16* h = (_Float16*)(wsb + 40960000);     // 10000x128
  _Float16* A0 = (_Float16*)(wsb + 43520000);    // 10000x64
  _Float16* wT = (_Float16*)(wsb + 44800000);    // 524288 f16
  int* counts = (int*)(wsb + 45848576);          // 10000
  Edge* edges = (Edge*)(wsb + 45888576);         // 10000 x CAP(64) x 8B = 5.12 MB

  _Float16* w0T = wT + 0;        // [1536][64]
  _Float16* wqkv1T = wT + 98304; // [1536][128]
  _Float16* wo0T = wT + 294912;  // [128][512]
  _Float16* wo1T = wT + 360448;  // [128][512]
  _Float16* w1T = wT + 425984;   // [256][128]
  _Float16* w2T = wT + 458752;   // [256][256]

  const int* e_src = eidx;
  const int* e_dst = eidx + NE;

  // fused prep (weights + pack + counts zero + out=b3), then bucket scatter
  prep_kernel<<<4666, 256, 0, stream>>>(wq0, wk0, wv0, wo0, wq1, wk1, wv1, wo1, w1, w2, wT, obs, A0,
                                        counts, b3, outp);
  scatter_kernel<<<(NE + 255) / 256, 256, 0, stream>>>(e_src, e_dst, obs, counts, edges);

  // layer 0: qkv (XCD-pinned SPLIT), GAT, out-proj (segmented head-major A, BM=32)
  gemm_mfma<128, 0, 0, 1, 0, 1><<<1896, 256, 0, stream>>>(A0, w0T, nullptr, qh, KVB, NN, 1536, 64);
  gat_kernel<<<10000, 256, 0, stream>>>(qh, KVB, counts, edges, attH);
  gemm_mfma<32, 1, 0, 0, 1, 0><<<dim3(313, 2), 256, 0, stream>>>(attH, wo0T, bo0, h, nullptr, NN, 128, 512);

  // layer 1
  gemm_mfma<128, 0, 0, 1, 0, 1><<<1896, 256, 0, stream>>>(h, wqkv1T, nullptr, qh, KVB, NN, 1536, 128);
  gat_kernel<<<10000, 256, 0, stream>>>(qh, KVB, counts, edges, attH);
  gemm_mfma<32, 1, 0, 0, 1, 0><<<dim3(313, 2), 256, 0, stream>>>(attH, wo1T, bo1, h, nullptr, NN, 128, 512);

  // fused MLP: w1+w2+w3 in one kernel (out pre-initialized to b3)
  mlp_kernel<<<313, 256, 0, stream>>>(h, w1T, b1, w2T, b2, w3, outp);
}